// Round 1
// baseline (60586.261 us; speedup 1.0000x reference)
//
#include <hip/hip_runtime.h>
#include <hip/hip_bf16.h>
#include <math.h>

#define BB 32
#define SS 256
#define EE 512
#define HH 1024
#define LDM 256
#define NROW (BB*SS)   // 8192

// ---------------- sort (stable argsort by descending length) ----------------
__global__ void k_sort(const int* __restrict__ length, int* __restrict__ sorted_idx){
  int b = threadIdx.x;
  if (b >= BB) return;
  int lb = length[b];
  int r = 0;
  for (int o = 0; o < BB; ++o){
    int lo = length[o];
    if (lo > lb || (lo == lb && o < b)) ++r;
  }
  sorted_idx[r] = b;
}

// token / target maps in sorted order
__global__ void k_maps(const int* __restrict__ sorted_idx,
                       const int* __restrict__ inp_seq, const int* __restrict__ tgt_seq,
                       int* __restrict__ tokmap, int* __restrict__ tgtmap){
  int bs = blockIdx.x; int t = threadIdx.x;
  int b = sorted_idx[bs];
  tokmap[bs*SS + t] = inp_seq[b*SS + t];
  tgtmap[bs*SS + t] = tgt_seq[b*SS + t];
}

// hid = z @ l2h_w.T + l2h_b   -> flat [65536]
__global__ __launch_bounds__(256) void k_hid(const float* __restrict__ z,
        const float* __restrict__ w, const float* __restrict__ bias,
        float* __restrict__ hid){
  int id = blockIdx.x*256 + threadIdx.x;      // 0..65535
  int b = id >> 11, c = id & 2047;
  const float4* zr = (const float4*)(z + b*LDM);
  const float4* wr = (const float4*)(w + (size_t)c*LDM);
  float a0=0,a1=0,a2=0,a3=0;
  #pragma unroll 4
  for (int k=0;k<LDM/4;k++){ float4 zz=zr[k], ww=wr[k];
    a0+=zz.x*ww.x; a1+=zz.y*ww.y; a2+=zz.z*ww.z; a3+=zz.w*ww.w; }
  hid[id] = a0+a1+a2+a3 + bias[c];
}

// ---------------- generic tiled fp32 GEMM: C[M,N] = A[M,K] @ Bm[N,K]^T (+bias0+bias1)
// optional rowmap: A row r -> A + rowmap[r]*lda  (embedding gather)
// requires M%64==0, K%16==0; N arbitrary (guarded)
__global__ __launch_bounds__(256) void k_gemm(
    const float* __restrict__ A, int lda, const int* __restrict__ rowmap,
    const float* __restrict__ Bm,
    const float* __restrict__ bias0, const float* __restrict__ bias1,
    float* __restrict__ C, int M, int N, int K)
{
  __shared__ float As[16][64];
  __shared__ float Bs[16][64];
  int nt = blockIdx.x * 64, mt = blockIdx.y * 64;
  int t = threadIdx.x;
  int tn = t & 15, tm = t >> 4;
  int lr = t >> 2;          // 0..63
  int lk = (t & 3) * 4;     // 0,4,8,12
  float acc[4][4] = {{0.f}};
  for (int k0 = 0; k0 < K; k0 += 16){
    int ar = mt + lr;
    const float* ap = A + (size_t)(rowmap ? rowmap[ar] : ar) * lda + k0 + lk;
    float4 av = *(const float4*)ap;
    As[lk+0][lr]=av.x; As[lk+1][lr]=av.y; As[lk+2][lr]=av.z; As[lk+3][lr]=av.w;
    int bn = nt + lr;
    float4 bv = make_float4(0.f,0.f,0.f,0.f);
    if (bn < N) bv = *(const float4*)(Bm + (size_t)bn*K + k0 + lk);
    Bs[lk+0][lr]=bv.x; Bs[lk+1][lr]=bv.y; Bs[lk+2][lr]=bv.z; Bs[lk+3][lr]=bv.w;
    __syncthreads();
    #pragma unroll
    for (int k=0;k<16;k++){
      float4 a4 = *(const float4*)&As[k][tm*4];
      float4 b4 = *(const float4*)&Bs[k][tn*4];
      float a[4]={a4.x,a4.y,a4.z,a4.w}, bb[4]={b4.x,b4.y,b4.z,b4.w};
      #pragma unroll
      for (int i=0;i<4;i++)
        #pragma unroll
        for (int j=0;j<4;j++) acc[i][j] += a[i]*bb[j];
    }
    __syncthreads();
  }
  #pragma unroll
  for (int i=0;i<4;i++){
    int row = mt + tm*4 + i;
    #pragma unroll
    for (int j=0;j<4;j++){
      int col = nt + tn*4 + j;
      if (col < N){
        float v = acc[i][j];
        if (bias0) v += bias0[col];
        if (bias1) v += bias1[col];
        C[(size_t)row*N + col] = v;
      }
    }
  }
}

// ---------------- RNN recurrence, one workgroup per (sorted) batch, in place:
// buf holds pre-activations [32][256][1024]; overwritten with hidden states.
__global__ __launch_bounds__(1024) void k_rnn(float* __restrict__ buf,
        const float* __restrict__ whh, const float* __restrict__ hid, int layer)
{
  int bs = blockIdx.x;
  int j  = threadIdx.x;
  __shared__ float hs[HH];
  hs[j] = hid[layer*BB*HH + bs*HH + j];
  float* base = buf + (size_t)bs*SS*HH + j;
  const float4* wrow = (const float4*)(whh + (size_t)j*HH);
  __syncthreads();
  for (int t = 0; t < SS; ++t){
    float pre = base[(size_t)t*HH];
    const float4* hp = (const float4*)hs;
    float a0=0.f,a1=0.f,a2=0.f,a3=0.f;
    #pragma unroll 4
    for (int kq = 0; kq < HH/4; ++kq){
      float4 w = wrow[kq]; float4 h4 = hp[kq];
      a0 += w.x*h4.x; a1 += w.y*h4.y; a2 += w.z*h4.z; a3 += w.w*h4.w;
    }
    float hnew = tanhf(pre + a0+a1+a2+a3);
    __syncthreads();            // everyone done reading old hs
    hs[j] = hnew;
    base[(size_t)t*HH] = hnew;
    __syncthreads();            // new hs visible
  }
}

// ---------------- fused cluster logsumexp: per row, online max/sumexp over Nc logits
// logits = proj[row,:Kp] . W[n,:Kp].  One wave handles 4 rows (amortizes W reads).
__global__ __launch_bounds__(256) void k_cluster(
    const float* __restrict__ proj, int Kp,
    const float* __restrict__ W, int Nc,
    float* __restrict__ stats, int ci)
{
  __shared__ float ps[4][4][256];
  int lane = threadIdx.x & 63;
  int wvl  = threadIdx.x >> 6;           // wave in block 0..3
  int r0 = (blockIdx.x*4 + wvl) * 4;     // first of this wave's 4 rows
  for (int r=0;r<4;r++)
    for (int k=lane;k<Kp;k+=64)
      ps[wvl][r][k] = proj[(size_t)(r0+r)*Kp + k];
  __syncthreads();
  float mx[4], sm[4];
  #pragma unroll
  for (int r=0;r<4;r++){ mx[r]=-1e30f; sm[r]=0.f; }
  for (int n=lane; n<Nc; n+=64){
    const float* wr = W + (size_t)n*Kp;
    float l[4]={0.f,0.f,0.f,0.f};
    for (int k=0;k<Kp;k+=4){
      float4 w4 = *(const float4*)(wr+k);
      #pragma unroll
      for (int r=0;r<4;r++){
        l[r] += w4.x*ps[wvl][r][k] + w4.y*ps[wvl][r][k+1]
              + w4.z*ps[wvl][r][k+2] + w4.w*ps[wvl][r][k+3];
      }
    }
    #pragma unroll
    for (int r=0;r<4;r++){
      float nm = fmaxf(mx[r], l[r]);
      sm[r] = sm[r]*__expf(mx[r]-nm) + __expf(l[r]-nm);
      mx[r] = nm;
    }
  }
  #pragma unroll
  for (int r=0;r<4;r++){
    for (int off=32; off; off>>=1){
      float om = __shfl_down(mx[r], off);
      float os = __shfl_down(sm[r], off);
      float nm = fmaxf(mx[r], om);
      sm[r] = sm[r]*__expf(mx[r]-nm) + os*__expf(om-nm);
      mx[r] = nm;
    }
    if (lane==0){
      stats[(size_t)(r0+r)*6 + ci*2 + 0] = mx[r];
      stats[(size_t)(r0+r)*6 + ci*2 + 1] = sm[r];
    }
  }
}

// ---------------- target logit for tail clusters (one wave per row) ----------------
__global__ __launch_bounds__(256) void k_tlogit(
    const int* __restrict__ tgtmap,
    const float* __restrict__ proj0, const float* __restrict__ proj1, const float* __restrict__ proj2,
    const float* __restrict__ w0, const float* __restrict__ w1, const float* __restrict__ w2,
    float* __restrict__ tlogit)
{
  int lane = threadIdx.x & 63;
  int row = (blockIdx.x * 256 + threadIdx.x) >> 6;
  int tgt = tgtmap[row];
  float acc = 0.f;
  const float* pr = nullptr; const float* wr = nullptr; int Kp = 0;
  if      (tgt >= 1000){ pr = proj2 + (size_t)row*16;  wr = w2 + (size_t)(tgt-1000)*16;  Kp=16;  }
  else if (tgt >= 100) { pr = proj1 + (size_t)row*64;  wr = w1 + (size_t)(tgt-100)*64;   Kp=64;  }
  else if (tgt >= 30)  { pr = proj0 + (size_t)row*256; wr = w0 + (size_t)(tgt-30)*256;   Kp=256; }
  for (int k=lane; k<Kp; k+=64) acc += pr[k]*wr[k];
  for (int off=32; off; off>>=1) acc += __shfl_down(acc, off);
  if (lane==0) tlogit[row] = acc;
}

// ---------------- final: head LSE + assemble NLL, reduce ----------------
__global__ __launch_bounds__(256) void k_final(
    const float* __restrict__ head, const float* __restrict__ stats,
    const float* __restrict__ tlogit, const int* __restrict__ tgtmap,
    float* __restrict__ out)
{
  int row = blockIdx.x*256 + threadIdx.x;
  int tgt = tgtmap[row];
  float nll = 0.f;
  if (tgt != 0){
    const float* hrow = head + (size_t)row*33;
    float m = hrow[0];
    #pragma unroll
    for (int i=1;i<33;i++) m = fmaxf(m, hrow[i]);
    float s = 0.f;
    #pragma unroll
    for (int i=0;i<33;i++) s += __expf(hrow[i]-m);
    float lse = __logf(s) + m;
    int ci = (tgt>=1000) ? 2 : (tgt>=100) ? 1 : (tgt>=30) ? 0 : -1;
    if (ci < 0){
      nll = lse - hrow[tgt];
    } else {
      float cm = stats[(size_t)row*6 + ci*2 + 0];
      float cs = stats[(size_t)row*6 + ci*2 + 1];
      nll = lse - hrow[30+ci] + (__logf(cs) + cm - tlogit[row]);
    }
  }
  float v = nll;
  for (int off=32; off; off>>=1) v += __shfl_down(v, off);
  __shared__ float wsum[4];
  int lane = threadIdx.x & 63, wv = threadIdx.x >> 6;
  if (lane==0) wsum[wv] = v;
  __syncthreads();
  if (threadIdx.x==0) atomicAdd(out, wsum[0]+wsum[1]+wsum[2]+wsum[3]);
}

extern "C" void kernel_launch(void* const* d_in, const int* in_sizes, int n_in,
                              void* d_out, int out_size, void* d_ws, size_t ws_size,
                              hipStream_t stream)
{
  const float* z      = (const float*)d_in[0];
  const float* emb    = (const float*)d_in[1];
  const float* l2h_w  = (const float*)d_in[2];
  const float* l2h_b  = (const float*)d_in[3];
  const float* w0ih   = (const float*)d_in[4];
  const float* w0hh   = (const float*)d_in[5];
  const float* b0ih   = (const float*)d_in[6];
  const float* b0hh   = (const float*)d_in[7];
  const float* w1ih   = (const float*)d_in[8];
  const float* w1hh   = (const float*)d_in[9];
  const float* b1ih   = (const float*)d_in[10];
  const float* b1hh   = (const float*)d_in[11];
  const float* head_w = (const float*)d_in[12];
  const float* p0     = (const float*)d_in[13];
  const float* tw0    = (const float*)d_in[14];
  const float* p1     = (const float*)d_in[15];
  const float* tw1    = (const float*)d_in[16];
  const float* p2     = (const float*)d_in[17];
  const float* tw2    = (const float*)d_in[18];
  const int* inp_seq  = (const int*)d_in[19];
  const int* tgt_seq  = (const int*)d_in[20];
  const int* length   = (const int*)d_in[21];

  float* ws   = (float*)d_ws;
  float* hid  = ws;                               // 65536
  float* bufA = hid + 65536;                      // 8192*1024  (pre0 -> h1; later reused for head/proj/stats)
  float* bufB = bufA + (size_t)NROW*HH;           // 8192*1024  (pre1 -> h2)
  int*   ibuf = (int*)(bufB + (size_t)NROW*HH);
  int* sorted_idx = ibuf;                         // 32
  int* tokmap = ibuf + 32;                        // 8192
  int* tgtmap = tokmap + NROW;                    // 8192
  // aliased into bufA once h1 is consumed (after pre1 GEMM):
  float* headL = bufA;                            // 8192*33
  float* proj0 = headL + (size_t)NROW*33;         // 8192*256
  float* proj1 = proj0 + (size_t)NROW*256;        // 8192*64
  float* proj2 = proj1 + (size_t)NROW*64;         // 8192*16
  float* stats = proj2 + (size_t)NROW*16;         // 8192*6
  float* tlog  = stats + (size_t)NROW*6;          // 8192

  float* outF = (float*)d_out;
  hipMemsetAsync(outF, 0, sizeof(float), stream);

  k_sort<<<1, 32, 0, stream>>>(length, sorted_idx);
  k_maps<<<32, 256, 0, stream>>>(sorted_idx, inp_seq, tgt_seq, tokmap, tgtmap);
  k_hid<<<256, 256, 0, stream>>>(z, l2h_w, l2h_b, hid);

  // pre0 = emb[tok] @ w0ih^T + b0ih + b0hh
  k_gemm<<<dim3(HH/64, NROW/64), 256, 0, stream>>>(emb, EE, tokmap, w0ih, b0ih, b0hh,
                                                   bufA, NROW, HH, EE);
  k_rnn<<<32, 1024, 0, stream>>>(bufA, w0hh, hid, 0);          // bufA := h1
  // pre1 = h1 @ w1ih^T + b1ih + b1hh
  k_gemm<<<dim3(HH/64, NROW/64), 256, 0, stream>>>(bufA, HH, nullptr, w1ih, b1ih, b1hh,
                                                   bufB, NROW, HH, HH);
  k_rnn<<<32, 1024, 0, stream>>>(bufB, w1hh, hid, 1);          // bufB := h2

  // head logits + tail projections (A = h2, sorted order; targets gathered to match)
  k_gemm<<<dim3(1, NROW/64), 256, 0, stream>>>(bufB, HH, nullptr, head_w, nullptr, nullptr,
                                               headL, NROW, 33, HH);
  k_gemm<<<dim3(4, NROW/64), 256, 0, stream>>>(bufB, HH, nullptr, p0, nullptr, nullptr,
                                               proj0, NROW, 256, HH);
  k_gemm<<<dim3(1, NROW/64), 256, 0, stream>>>(bufB, HH, nullptr, p1, nullptr, nullptr,
                                               proj1, NROW, 64, HH);
  k_gemm<<<dim3(1, NROW/64), 256, 0, stream>>>(bufB, HH, nullptr, p2, nullptr, nullptr,
                                               proj2, NROW, 16, HH);

  k_cluster<<<NROW/16, 256, 0, stream>>>(proj0, 256, tw0, 70,    stats, 0);
  k_cluster<<<NROW/16, 256, 0, stream>>>(proj1, 64,  tw1, 900,   stats, 1);
  k_cluster<<<NROW/16, 256, 0, stream>>>(proj2, 16,  tw2, 19000, stats, 2);
  k_tlogit<<<NROW/4, 256, 0, stream>>>(tgtmap, proj0, proj1, proj2, tw0, tw1, tw2, tlog);
  k_final<<<NROW/256, 256, 0, stream>>>(headL, stats, tlog, tgtmap, outF);
}

// Round 2
// 5664.169 us; speedup vs baseline: 10.6964x; 10.6964x over previous
//
#include <hip/hip_runtime.h>
#include <hip/hip_bf16.h>
#include <math.h>

#define BB 32
#define SS 256
#define EE 512
#define HH 1024
#define LDM 256
#define NROW (BB*SS)   // 8192
#define NWG 64         // cooperative wgs for recurrence

typedef __attribute__((ext_vector_type(8))) short bf16x8;
typedef __attribute__((ext_vector_type(4))) float f32x4;

static __device__ inline unsigned short f2bf(float f){
  unsigned u = __float_as_uint(f);
  unsigned r = (u + 0x7fffu + ((u >> 16) & 1u)) >> 16;
  return (unsigned short)r;
}

// ---------------- sort (stable argsort by descending length) ----------------
__global__ void k_sort(const int* __restrict__ length, int* __restrict__ sorted_idx){
  int b = threadIdx.x;
  if (b >= BB) return;
  int lb = length[b];
  int r = 0;
  for (int o = 0; o < BB; ++o){
    int lo = length[o];
    if (lo > lb || (lo == lb && o < b)) ++r;
  }
  sorted_idx[r] = b;
}

// token / target maps in sorted order
__global__ void k_maps(const int* __restrict__ sorted_idx,
                       const int* __restrict__ inp_seq, const int* __restrict__ tgt_seq,
                       int* __restrict__ tokmap, int* __restrict__ tgtmap){
  int bs = blockIdx.x; int t = threadIdx.x;
  int b = sorted_idx[bs];
  tokmap[bs*SS + t] = inp_seq[b*SS + t];
  tgtmap[bs*SS + t] = tgt_seq[b*SS + t];
}

// hid = z @ l2h_w.T + l2h_b, written DIRECTLY in bf16 fragment-major layout
// hb0[layer][ (j>>3)*256 + b'*8 + (j&7) ]  matching MFMA A-frag reads.
__global__ __launch_bounds__(256) void k_hid(const float* __restrict__ z,
        const float* __restrict__ w, const float* __restrict__ bias,
        ushort* __restrict__ hb0){
  int id = blockIdx.x*256 + threadIdx.x;      // flat [B,2H] index = b*2048 + c
  int b = id >> 11, c = id & 2047;
  const float4* zr = (const float4*)(z + b*LDM);
  const float4* wr = (const float4*)(w + (size_t)c*LDM);
  float a0=0,a1=0,a2=0,a3=0;
  #pragma unroll 4
  for (int k=0;k<LDM/4;k++){ float4 zz=zr[k], ww=wr[k];
    a0+=zz.x*ww.x; a1+=zz.y*ww.y; a2+=zz.z*ww.z; a3+=zz.w*ww.w; }
  float val = a0+a1+a2+a3 + bias[c];
  // reshape(NL,B,H) of the flat [B,2H] array:
  int layer = id >> 15, bp = (id >> 10) & 31, j = id & 1023;
  hb0[(layer<<15) + ((j>>3)<<8) + (bp<<3) + (j&7)] = f2bf(val);
}

// ---------------- generic tiled fp32 GEMM: C[M,N] = A[M,K] @ Bm[N,K]^T (+bias0+bias1)
__global__ __launch_bounds__(256) void k_gemm(
    const float* __restrict__ A, int lda, const int* __restrict__ rowmap,
    const float* __restrict__ Bm,
    const float* __restrict__ bias0, const float* __restrict__ bias1,
    float* __restrict__ C, int M, int N, int K)
{
  __shared__ float As[16][64];
  __shared__ float Bs[16][64];
  int nt = blockIdx.x * 64, mt = blockIdx.y * 64;
  int t = threadIdx.x;
  int tn = t & 15, tm = t >> 4;
  int lr = t >> 2;          // 0..63
  int lk = (t & 3) * 4;     // 0,4,8,12
  float acc[4][4] = {{0.f}};
  for (int k0 = 0; k0 < K; k0 += 16){
    int ar = mt + lr;
    const float* ap = A + (size_t)(rowmap ? rowmap[ar] : ar) * lda + k0 + lk;
    float4 av = *(const float4*)ap;
    As[lk+0][lr]=av.x; As[lk+1][lr]=av.y; As[lk+2][lr]=av.z; As[lk+3][lr]=av.w;
    int bn = nt + lr;
    float4 bv = make_float4(0.f,0.f,0.f,0.f);
    if (bn < N) bv = *(const float4*)(Bm + (size_t)bn*K + k0 + lk);
    Bs[lk+0][lr]=bv.x; Bs[lk+1][lr]=bv.y; Bs[lk+2][lr]=bv.z; Bs[lk+3][lr]=bv.w;
    __syncthreads();
    #pragma unroll
    for (int k=0;k<16;k++){
      float4 a4 = *(const float4*)&As[k][tm*4];
      float4 b4 = *(const float4*)&Bs[k][tn*4];
      float a[4]={a4.x,a4.y,a4.z,a4.w}, bb[4]={b4.x,b4.y,b4.z,b4.w};
      #pragma unroll
      for (int i=0;i<4;i++)
        #pragma unroll
        for (int j=0;j<4;j++) acc[i][j] += a[i]*bb[j];
    }
    __syncthreads();
  }
  #pragma unroll
  for (int i=0;i<4;i++){
    int row = mt + tm*4 + i;
    #pragma unroll
    for (int j=0;j<4;j++){
      int col = nt + tn*4 + j;
      if (col < N){
        float v = acc[i][j];
        if (bias0) v += bias0[col];
        if (bias1) v += bias1[col];
        C[(size_t)row*N + col] = v;
      }
    }
  }
}

// ---------------- cooperative persistent RNN recurrence ----------------
// 64 wgs; wg owns rows j0..j0+15 of Whh (bf16 in LDS, loaded once).
// Per step: slice GEMM via MFMA (4 waves split K), reduce in LDS, tanh,
// write h to fp32 buf (in place over pre) and bf16 ping-pong frag buffer.
// Grid barrier: per-wg flags, agent-scope atomics.
__global__ __launch_bounds__(256) void k_rnn_coop(
    float* __restrict__ buf, const float* __restrict__ whh,
    const ushort* __restrict__ hb0, ushort* __restrict__ hbP,
    int* flags, int layer)
{
  __shared__ ushort whh_s[16*1032];   // padded rows: stride 1032 -> 2-way banks, free
  __shared__ float red[4*512];
  const int wg  = blockIdx.x;
  const int tid = threadIdx.x;
  const int j0  = wg * 16;

  // load + convert Whh slice once (16 rows x 1024 fp32 -> bf16)
  for (int c = tid; c < 4096; c += 256){
    int r = c >> 8, cc = (c & 255) * 4;
    float4 w4 = *(const float4*)&whh[(size_t)(j0 + r)*HH + cc];
    uint2 p;
    p.x = (unsigned)f2bf(w4.x) | ((unsigned)f2bf(w4.y) << 16);
    p.y = (unsigned)f2bf(w4.z) | ((unsigned)f2bf(w4.w) << 16);
    *(uint2*)&whh_s[r*1032 + cc] = p;
  }
  const int lane = tid & 63, wv = tid >> 6;
  const int col = lane & 15, quad = lane >> 4;
  const int kw = wv * 256;                 // this wave's K quarter
  const ushort* src0 = hb0 + (layer << 15);
  __syncthreads();

  for (int t = 0; t < SS; ++t){
    const ushort* src = (t == 0) ? src0 : hbP + (1 - (t & 1)) * 32768;
    ushort* dst = hbP + (t & 1) * 32768;

    // prefetch this thread's pre-activations (hidden by MFMA phase)
    int ob0 = tid >> 4,        oj = tid & 15;
    float pre0 = buf[((size_t)ob0*SS + t)*HH + j0 + oj];
    float pre1 = buf[((size_t)(ob0+16)*SS + t)*HH + j0 + oj];

    f32x4 acc0 = {0.f,0.f,0.f,0.f}, acc1 = {0.f,0.f,0.f,0.f};
    #pragma unroll
    for (int ks = 0; ks < 8; ++ks){
      int kk = kw + ks*32 + quad*8;
      bf16x8 bfr = *(const bf16x8*)&whh_s[col*1032 + kk];         // B[k][n=j]
      int fb = (kk >> 3) << 8;                                     // frag-major base
      bf16x8 a0 = *(const bf16x8*)&src[fb + (col << 3)];           // A[b=col][k]
      bf16x8 a1 = *(const bf16x8*)&src[fb + ((col + 16) << 3)];    // A[b=col+16][k]
      acc0 = __builtin_amdgcn_mfma_f32_16x16x32_bf16(a0, bfr, acc0, 0, 0, 0);
      acc1 = __builtin_amdgcn_mfma_f32_16x16x32_bf16(a1, bfr, acc1, 0, 0, 0);
    }
    // partials to LDS: red[wv][b*16 + j]; C/D layout: row(b)=quad*4+r, col(j)=lane&15
    #pragma unroll
    for (int r = 0; r < 4; ++r){
      red[wv*512 + (quad*4 + r)*16 + col]        = acc0[r];
      red[wv*512 + (16 + quad*4 + r)*16 + col]   = acc1[r];
    }
    __syncthreads();

    // reduce 4 waves, tanh, store (o = b*16 + j -> coalesced 64B runs)
    #pragma unroll
    for (int i = 0; i < 2; ++i){
      int o = tid + i*256;
      float s = red[o] + red[512 + o] + red[1024 + o] + red[1536 + o];
      int b = o >> 4, j = o & 15;
      float v = tanhf((i ? pre1 : pre0) + s);
      buf[((size_t)b*SS + t)*HH + j0 + j] = v;     // fp32 h (in place over pre)
      int k = j0 + j;
      dst[((k >> 3) << 8) + (b << 3) + (k & 7)] = f2bf(v);  // frag-major bf16
    }
    __syncthreads();

    // grid barrier (agent scope: handles per-XCD L2 non-coherence)
    if (tid == 0)
      __hip_atomic_store(&flags[wg], t + 1, __ATOMIC_RELEASE, __HIP_MEMORY_SCOPE_AGENT);
    if (tid < NWG){
      while (__hip_atomic_load(&flags[tid], __ATOMIC_RELAXED, __HIP_MEMORY_SCOPE_AGENT) < t + 1)
        __builtin_amdgcn_s_sleep(2);
    }
    __syncthreads();
    __threadfence();   // acquire: invalidate stale L1/L2 before reading peers' h
  }
}

// ---------------- fused cluster logsumexp ----------------
__global__ __launch_bounds__(256) void k_cluster(
    const float* __restrict__ proj, int Kp,
    const float* __restrict__ W, int Nc,
    float* __restrict__ stats, int ci)
{
  __shared__ float ps[4][4][256];
  int lane = threadIdx.x & 63;
  int wvl  = threadIdx.x >> 6;           // wave in block 0..3
  int r0 = (blockIdx.x*4 + wvl) * 4;     // first of this wave's 4 rows
  for (int r=0;r<4;r++)
    for (int k=lane;k<Kp;k+=64)
      ps[wvl][r][k] = proj[(size_t)(r0+r)*Kp + k];
  __syncthreads();
  float mx[4], sm[4];
  #pragma unroll
  for (int r=0;r<4;r++){ mx[r]=-1e30f; sm[r]=0.f; }
  for (int n=lane; n<Nc; n+=64){
    const float* wr = W + (size_t)n*Kp;
    float l[4]={0.f,0.f,0.f,0.f};
    for (int k=0;k<Kp;k+=4){
      float4 w4 = *(const float4*)(wr+k);
      #pragma unroll
      for (int r=0;r<4;r++){
        l[r] += w4.x*ps[wvl][r][k] + w4.y*ps[wvl][r][k+1]
              + w4.z*ps[wvl][r][k+2] + w4.w*ps[wvl][r][k+3];
      }
    }
    #pragma unroll
    for (int r=0;r<4;r++){
      float nm = fmaxf(mx[r], l[r]);
      sm[r] = sm[r]*__expf(mx[r]-nm) + __expf(l[r]-nm);
      mx[r] = nm;
    }
  }
  #pragma unroll
  for (int r=0;r<4;r++){
    for (int off=32; off; off>>=1){
      float om = __shfl_down(mx[r], off);
      float os = __shfl_down(sm[r], off);
      float nm = fmaxf(mx[r], om);
      sm[r] = sm[r]*__expf(mx[r]-nm) + os*__expf(om-nm);
      mx[r] = nm;
    }
    if (lane==0){
      stats[(size_t)(r0+r)*6 + ci*2 + 0] = mx[r];
      stats[(size_t)(r0+r)*6 + ci*2 + 1] = sm[r];
    }
  }
}

// ---------------- target logit for tail clusters (one wave per row) ----------------
__global__ __launch_bounds__(256) void k_tlogit(
    const int* __restrict__ tgtmap,
    const float* __restrict__ proj0, const float* __restrict__ proj1, const float* __restrict__ proj2,
    const float* __restrict__ w0, const float* __restrict__ w1, const float* __restrict__ w2,
    float* __restrict__ tlogit)
{
  int lane = threadIdx.x & 63;
  int row = (blockIdx.x * 256 + threadIdx.x) >> 6;
  int tgt = tgtmap[row];
  float acc = 0.f;
  const float* pr = nullptr; const float* wr = nullptr; int Kp = 0;
  if      (tgt >= 1000){ pr = proj2 + (size_t)row*16;  wr = w2 + (size_t)(tgt-1000)*16;  Kp=16;  }
  else if (tgt >= 100) { pr = proj1 + (size_t)row*64;  wr = w1 + (size_t)(tgt-100)*64;   Kp=64;  }
  else if (tgt >= 30)  { pr = proj0 + (size_t)row*256; wr = w0 + (size_t)(tgt-30)*256;   Kp=256; }
  for (int k=lane; k<Kp; k+=64) acc += pr[k]*wr[k];
  for (int off=32; off; off>>=1) acc += __shfl_down(acc, off);
  if (lane==0) tlogit[row] = acc;
}

// ---------------- final: head LSE + assemble NLL, reduce ----------------
__global__ __launch_bounds__(256) void k_final(
    const float* __restrict__ head, const float* __restrict__ stats,
    const float* __restrict__ tlogit, const int* __restrict__ tgtmap,
    float* __restrict__ out)
{
  int row = blockIdx.x*256 + threadIdx.x;
  int tgt = tgtmap[row];
  float nll = 0.f;
  if (tgt != 0){
    const float* hrow = head + (size_t)row*33;
    float m = hrow[0];
    #pragma unroll
    for (int i=1;i<33;i++) m = fmaxf(m, hrow[i]);
    float s = 0.f;
    #pragma unroll
    for (int i=0;i<33;i++) s += __expf(hrow[i]-m);
    float lse = __logf(s) + m;
    int ci = (tgt>=1000) ? 2 : (tgt>=100) ? 1 : (tgt>=30) ? 0 : -1;
    if (ci < 0){
      nll = lse - hrow[tgt];
    } else {
      float cm = stats[(size_t)row*6 + ci*2 + 0];
      float cs = stats[(size_t)row*6 + ci*2 + 1];
      nll = lse - hrow[30+ci] + (__logf(cs) + cm - tlogit[row]);
    }
  }
  float v = nll;
  for (int off=32; off; off>>=1) v += __shfl_down(v, off);
  __shared__ float wsum[4];
  int lane = threadIdx.x & 63, wv = threadIdx.x >> 6;
  if (lane==0) wsum[wv] = v;
  __syncthreads();
  if (threadIdx.x==0) atomicAdd(out, wsum[0]+wsum[1]+wsum[2]+wsum[3]);
}

extern "C" void kernel_launch(void* const* d_in, const int* in_sizes, int n_in,
                              void* d_out, int out_size, void* d_ws, size_t ws_size,
                              hipStream_t stream)
{
  const float* z      = (const float*)d_in[0];
  const float* emb    = (const float*)d_in[1];
  const float* l2h_w  = (const float*)d_in[2];
  const float* l2h_b  = (const float*)d_in[3];
  const float* w0ih   = (const float*)d_in[4];
  const float* w0hh   = (const float*)d_in[5];
  const float* b0ih   = (const float*)d_in[6];
  const float* b0hh   = (const float*)d_in[7];
  const float* w1ih   = (const float*)d_in[8];
  const float* w1hh   = (const float*)d_in[9];
  const float* b1ih   = (const float*)d_in[10];
  const float* b1hh   = (const float*)d_in[11];
  const float* head_w = (const float*)d_in[12];
  const float* p0     = (const float*)d_in[13];
  const float* tw0    = (const float*)d_in[14];
  const float* p1     = (const float*)d_in[15];
  const float* tw1    = (const float*)d_in[16];
  const float* p2     = (const float*)d_in[17];
  const float* tw2    = (const float*)d_in[18];
  const int* inp_seq  = (const int*)d_in[19];
  const int* tgt_seq  = (const int*)d_in[20];
  const int* length   = (const int*)d_in[21];

  float* ws   = (float*)d_ws;
  // hb0 (h0 in frag layout, both layers) + hbP (ping-pong) overlay the old
  // 65536-float hid region exactly (262144 B).
  ushort* hb0 = (ushort*)ws;                      // 65536 ushorts
  ushort* hbP = hb0 + 65536;                      // 65536 ushorts
  float* bufA = ws + 65536;                       // 8192*1024  (pre0 -> h1; later head/proj/stats)
  float* bufB = bufA + (size_t)NROW*HH;           // 8192*1024  (pre1 -> h2)
  int*   ibuf = (int*)(bufB + (size_t)NROW*HH);
  int* sorted_idx = ibuf;                         // 32
  int* tokmap = ibuf + 32;                        // 8192
  int* tgtmap = tokmap + NROW;                    // 8192
  int* flags  = tgtmap + NROW;                    // 128 (2 layers x 64)
  // aliased into bufA once h1 is consumed (after pre1 GEMM):
  float* headL = bufA;                            // 8192*33
  float* proj0 = headL + (size_t)NROW*33;         // 8192*256
  float* proj1 = proj0 + (size_t)NROW*256;        // 8192*64
  float* proj2 = proj1 + (size_t)NROW*64;         // 8192*16
  float* stats = proj2 + (size_t)NROW*16;         // 8192*6
  float* tlog  = stats + (size_t)NROW*6;          // 8192

  float* outF = (float*)d_out;
  hipMemsetAsync(outF, 0, sizeof(float), stream);
  hipMemsetAsync(flags, 0, 128*sizeof(int), stream);

  k_sort<<<1, 32, 0, stream>>>(length, sorted_idx);
  k_maps<<<32, 256, 0, stream>>>(sorted_idx, inp_seq, tgt_seq, tokmap, tgtmap);
  k_hid<<<256, 256, 0, stream>>>(z, l2h_w, l2h_b, hb0);

  // pre0 = emb[tok] @ w0ih^T + b0ih + b0hh
  k_gemm<<<dim3(HH/64, NROW/64), 256, 0, stream>>>(emb, EE, tokmap, w0ih, b0ih, b0hh,
                                                   bufA, NROW, HH, EE);
  k_rnn_coop<<<NWG, 256, 0, stream>>>(bufA, w0hh, hb0, hbP, flags, 0);      // bufA := h1
  // pre1 = h1 @ w1ih^T + b1ih + b1hh
  k_gemm<<<dim3(HH/64, NROW/64), 256, 0, stream>>>(bufA, HH, nullptr, w1ih, b1ih, b1hh,
                                                   bufB, NROW, HH, HH);
  k_rnn_coop<<<NWG, 256, 0, stream>>>(bufB, w1hh, hb0, hbP, flags + 64, 1); // bufB := h2

  // head logits + tail projections
  k_gemm<<<dim3(1, NROW/64), 256, 0, stream>>>(bufB, HH, nullptr, head_w, nullptr, nullptr,
                                               headL, NROW, 33, HH);
  k_gemm<<<dim3(4, NROW/64), 256, 0, stream>>>(bufB, HH, nullptr, p0, nullptr, nullptr,
                                               proj0, NROW, 256, HH);
  k_gemm<<<dim3(1, NROW/64), 256, 0, stream>>>(bufB, HH, nullptr, p1, nullptr, nullptr,
                                               proj1, NROW, 64, HH);
  k_gemm<<<dim3(1, NROW/64), 256, 0, stream>>>(bufB, HH, nullptr, p2, nullptr, nullptr,
                                               proj2, NROW, 16, HH);

  k_cluster<<<NROW/16, 256, 0, stream>>>(proj0, 256, tw0, 70,    stats, 0);
  k_cluster<<<NROW/16, 256, 0, stream>>>(proj1, 64,  tw1, 900,   stats, 1);
  k_cluster<<<NROW/16, 256, 0, stream>>>(proj2, 16,  tw2, 19000, stats, 2);
  k_tlogit<<<NROW/4, 256, 0, stream>>>(tgtmap, proj0, proj1, proj2, tw0, tw1, tw2, tlog);
  k_final<<<NROW/256, 256, 0, stream>>>(headL, stats, tlog, tgtmap, outF);
}